// Round 5
// baseline (457.348 us; speedup 1.0000x reference)
//
#include <hip/hip_runtime.h>
#include <hip/hip_bf16.h>

#define B_ 4
#define T_ 128
#define HID 2560
#define NH 8
#define NKV 4
#define HD 256
#define INTER 10240
#define MROWS 512
#define EPS 1e-6f

typedef float f32x4 __attribute__((ext_vector_type(4)));
typedef __bf16 bf16x8 __attribute__((ext_vector_type(8)));

__device__ __forceinline__ unsigned short f2bf(float f){
  unsigned int u = __builtin_bit_cast(unsigned int, f);
  u += 0x7fffu + ((u >> 16) & 1u);
  return (unsigned short)(u >> 16);
}

__device__ __forceinline__ unsigned int cvtpk(float lo, float hi){
  unsigned int r;
  asm("v_cvt_pk_bf16_f32 %0, %1, %2" : "=v"(r) : "v"(lo), "v"(hi));
  return r;
}

__device__ __forceinline__ void glds16(const void* g, void* l){
  __builtin_amdgcn_global_load_lds(
      (const __attribute__((address_space(1))) void*)g,
      (__attribute__((address_space(3))) void*)l, 16, 0, 0);
}

__device__ __forceinline__ float bsum256(float v, float* buf){
  #pragma unroll
  for (int o = 32; o; o >>= 1) v += __shfl_xor(v, o);
  __syncthreads();
  if ((threadIdx.x & 63) == 0) buf[threadIdx.x >> 6] = v;
  __syncthreads();
  return buf[0] + buf[1] + buf[2] + buf[3];
}

// ---------------- K1: input RMSNorm -> bf16 ----------------
__global__ __launch_bounds__(256) void rms_in(
    const float* __restrict__ x, const float* __restrict__ w,
    unsigned short* __restrict__ out)
{
  __shared__ float buf[4];
  const int r = blockIdx.x, tid = threadIdx.x;
  const float* xp = x + (size_t)r * HID;
  float v[10]; float ss = 0.f;
  #pragma unroll
  for (int j = 0; j < 10; j++){ v[j] = xp[tid + j*256]; ss += v[j]*v[j]; }
  ss = bsum256(ss, buf);
  float s = rsqrtf(ss * (1.f/HID) + EPS);
  #pragma unroll
  for (int j = 0; j < 10; j++){
    int i = tid + j*256;
    out[(size_t)r*HID + i] = f2bf(v[j] * s * (1.f + w[i]));
  }
}

// ---------------- GEMM: C[split][M][N] = A(bf16,[M][K]) * B(fp32,[N][K])^T ----------------
// 128Mx64N tile, BK=32, 4 waves (2Mx2N). global_load_lds staging, 3-deep LDS
// pipeline, counted s_waitcnt vmcnt(4) + raw s_barrier (1 barrier/iter).
// A LDS: linear [128][32] bf16 (bank-uniform for frag reads).
// B LDS: [64][32] f32 with chunk^=(row&7) XOR swizzle on BOTH glds-source and ds_read.
__global__ __launch_bounds__(256) void gemm_bf16(
    const unsigned short* __restrict__ A,
    const float* __restrict__ Bw,
    float* __restrict__ C,
    int N, int K, int klen)
{
  __shared__ unsigned short As[3][128*32];   // 8KB each
  __shared__ float          Bs[3][64*32];    // 8KB each
  const int tid = threadIdx.x;
  const int bid = (blockIdx.x & 7) * ((int)gridDim.x >> 3) + (blockIdx.x >> 3);
  const int bm = (bid & 3) << 7;
  const int bn = (bid >> 2) << 6;
  const int k0 = blockIdx.y * klen;
  const int nt = klen >> 5;

  const int w = tid >> 6, l = tid & 63;
  // A staging: instr i covers rows i*64 + w*16 + (l>>2), 16B chunk (l&3)
  const int arow = w*16 + (l >> 2);
  const unsigned short* ApG = A + (size_t)(bm + arow) * K + k0 + ((l & 3) << 3);
  // B staging: instr i covers rows i*32 + w*8 + (l>>3), swizzled 16B chunk
  const int brow = w*8 + (l >> 3);
  const int bchunk = (l & 7) ^ (l >> 3);
  const float* BpG = Bw + (size_t)(bn + brow) * K + k0 + (bchunk << 2);

  const int wave = w, lane = l;
  const int wm = (wave & 1) << 6;
  const int wn = (wave >> 1) << 5;
  const int fr = lane & 15, kq = lane >> 4;
  const int sw = fr & 7;
  const int boff0 = ((2*kq) ^ sw) << 4;   // first 16B chunk of this kq, swizzled
  // second chunk: boff0 ^ 16

  f32x4 acc[4][2];
  #pragma unroll
  for (int i = 0; i < 4; i++)
    #pragma unroll
    for (int j = 0; j < 2; j++)
      #pragma unroll
      for (int e = 0; e < 4; e++) acc[i][j][e] = 0.f;

  auto STAGE = [&](int tt, int cur){
    const unsigned short* ag = ApG + (tt << 5);
    const float*          bg = BpG + (tt << 5);
    char* al = (char*)&As[cur][0] + (w << 10);
    char* bl = (char*)&Bs[cur][0] + (w << 10);
    glds16(ag,                 al);
    glds16(ag + ((size_t)K<<6), al + 4096);   // +64 rows
    glds16(bg,                 bl);
    glds16(bg + ((size_t)K<<5), bl + 4096);   // +32 rows
  };

  auto COMPUTE = [&](int cur){
    const char* ab = (const char*)&As[cur][0];
    const char* bb = (const char*)&Bs[cur][0];
    bf16x8 af[4], bfv[2];
    #pragma unroll
    for (int mi = 0; mi < 4; mi++)
      af[mi] = *(const bf16x8*)(ab + ((wm + mi*16 + fr) << 6) + (kq << 4));
    #pragma unroll
    for (int ni = 0; ni < 2; ni++){
      const char* rb = bb + ((wn + ni*16 + fr) << 7);
      f32x4 x0 = *(const f32x4*)(rb + boff0);
      f32x4 x1 = *(const f32x4*)(rb + (boff0 ^ 16));
      union { unsigned int u[4]; bf16x8 v; } pk;
      pk.u[0] = cvtpk(x0[0], x0[1]);
      pk.u[1] = cvtpk(x0[2], x0[3]);
      pk.u[2] = cvtpk(x1[0], x1[1]);
      pk.u[3] = cvtpk(x1[2], x1[3]);
      bfv[ni] = pk.v;
    }
    #pragma unroll
    for (int mi = 0; mi < 4; mi++)
      #pragma unroll
      for (int ni = 0; ni < 2; ni++)
        acc[mi][ni] = __builtin_amdgcn_mfma_f32_16x16x32_bf16(af[mi], bfv[ni], acc[mi][ni], 0, 0, 0);
  };

  STAGE(0, 0);
  if (nt > 1) STAGE(1, 1);
  int cur = 0;
  for (int t = 0; t < nt - 1; t++) {
    asm volatile("s_waitcnt vmcnt(4)" ::: "memory");   // tile t landed; t+1 (4 ops) stays in flight
    __builtin_amdgcn_s_barrier();
    __builtin_amdgcn_sched_barrier(0);
    if (t + 2 < nt) STAGE(t + 2, cur ? cur - 1 : 2);   // (cur+2)%3 — FIXED rotation
    COMPUTE(cur);
    cur = (cur == 2) ? 0 : cur + 1;
  }
  asm volatile("s_waitcnt vmcnt(0)" ::: "memory");
  __builtin_amdgcn_s_barrier();
  __builtin_amdgcn_sched_barrier(0);
  COMPUTE(cur);

  float* Cp = C + (size_t)blockIdx.y * MROWS * N;
  #pragma unroll
  for (int mi = 0; mi < 4; mi++) {
    #pragma unroll
    for (int ni = 0; ni < 2; ni++) {
      int m = bm + wm + mi*16 + kq*4;
      int n = bn + wn + ni*16 + fr;
      #pragma unroll
      for (int i = 0; i < 4; i++)
        Cp[(size_t)(m + i) * N + n] = acc[mi][ni][i];
    }
  }
}

// ---------------- K3: sum qkv splits (4), QK-norm, RoPE, scatter to q / kT / v ----------------
__global__ __launch_bounds__(64) void qkv_post(
    const float* __restrict__ qkvp,   // [4][512][4096]
    const float* __restrict__ fcos, const float* __restrict__ fsin,
    const float* __restrict__ qnw, const float* __restrict__ knw,
    float* __restrict__ qout, float* __restrict__ kT, float* __restrict__ vout)
{
  const int row = blockIdx.x;
  const int hh  = blockIdx.y;
  const int b = row >> 7, t = row & 127;
  const int l = threadIdx.x;
  const size_t MS = (size_t)MROWS * 4096;
  const float* src = qkvp + (size_t)row * 4096 + hh * 256;
  float x[4];
  #pragma unroll
  for (int j = 0; j < 4; j++){
    int d = l + j*64;
    x[j] = src[d] + src[d + MS] + src[d + 2*MS] + src[d + 3*MS];
  }
  if (hh >= 12) {
    float* vp = vout + ((size_t)(b*NKV + (hh-12)) * T_ + t) * HD;
    #pragma unroll
    for (int j = 0; j < 4; j++) vp[l + j*64] = x[j];
    return;
  }
  float ss = x[0]*x[0] + x[1]*x[1] + x[2]*x[2] + x[3]*x[3];
  #pragma unroll
  for (int o = 32; o; o >>= 1) ss += __shfl_xor(ss, o);
  float r = rsqrtf(ss * (1.f/HD) + EPS);
  const float* nw = (hh < 8) ? qnw : knw;
  #pragma unroll
  for (int j = 0; j < 4; j++){ int d = l + j*64; x[j] = x[j] * r * (1.f + nw[d]); }
  float c0 = fcos[t*128 + l],      s0 = fsin[t*128 + l];
  float c1 = fcos[t*128 + l + 64], s1 = fsin[t*128 + l + 64];
  float y0 = x[0]*c0 - x[2]*s0;
  float y2 = x[0]*s0 + x[2]*c0;
  float y1 = x[1]*c1 - x[3]*s1;
  float y3 = x[1]*s1 + x[3]*c1;
  if (hh < 8) {
    float* qp = qout + ((size_t)(b*NH + hh) * T_ + t) * HD;
    const float sc = 0.0625f;
    qp[l] = y0*sc; qp[l+64] = y1*sc; qp[l+128] = y2*sc; qp[l+192] = y3*sc;
  } else {
    float* kp = kT + (size_t)(b*NKV + (hh-8)) * HD * T_;
    kp[(size_t)(l)*T_ + t] = y0;  kp[(size_t)(l+64)*T_ + t] = y1;
    kp[(size_t)(l+128)*T_ + t] = y2; kp[(size_t)(l+192)*T_ + t] = y3;
  }
}

// ---------------- K4: causal attention over the 128 written positions ----------------
__global__ __launch_bounds__(128) void attn_fwd(
    const float* __restrict__ q, const float* __restrict__ kT,
    const float* __restrict__ V, unsigned short* __restrict__ attn_out)
{
  const int id = blockIdx.x;
  const int t = id & 127;
  const int h = (id >> 7) & 7;
  const int b = id >> 10;
  const int kvh = h >> 1;
  const int tid = threadIdx.x;
  __shared__ float qs[256];
  __shared__ float sc[128];
  __shared__ float red[128];
  const float* qp = q + (size_t)id * HD;
  qs[tid] = qp[tid]; qs[tid + 128] = qp[tid + 128];
  __syncthreads();
  const float* kp = kT + (size_t)(b*NKV + kvh) * HD * T_;
  float dot = 0.f;
  const bool valid = (tid <= t);
  if (valid) {
    #pragma unroll 8
    for (int d = 0; d < 256; d++) dot += qs[d] * kp[(size_t)d*T_ + tid];
  }
  float score = valid ? 50.f * tanhf(dot * 0.02f) : -3.0e38f;
  sc[tid] = score; red[tid] = score;
  __syncthreads();
  for (int o = 64; o; o >>= 1){ if (tid < o) red[tid] = fmaxf(red[tid], red[tid+o]); __syncthreads(); }
  float m = red[0];
  __syncthreads();
  float p = valid ? __expf(score - m) : 0.f;
  sc[tid] = p; red[tid] = p;
  __syncthreads();
  for (int o = 64; o; o >>= 1){ if (tid < o) red[tid] += red[tid+o]; __syncthreads(); }
  float inv = 1.f / red[0];
  const float* vp = V + (size_t)(b*NKV + kvh) * T_ * HD;
  float a0 = 0.f, a1 = 0.f;
  for (int s = 0; s <= t; s++){
    float ps = sc[s];
    a0 += ps * vp[(size_t)s*HD + tid];
    a1 += ps * vp[(size_t)s*HD + tid + 128];
  }
  size_t orow = ((size_t)(b*T_ + t)) * 2048 + h * 256;
  attn_out[orow + tid]       = f2bf(a0 * inv);
  attn_out[orow + tid + 128] = f2bf(a1 * inv);
}

// ---------------- K6: sum o splits (8), post-attn norm + residual, pre-ffw norm -> bf16 ----------------
__global__ __launch_bounds__(256) void post_attn_k(
    const float* __restrict__ op, const float* __restrict__ hs,
    const float* __restrict__ wpost, const float* __restrict__ wpre,
    float* __restrict__ h2, unsigned short* __restrict__ xout)
{
  __shared__ float buf[4];
  const int r = blockIdx.x, tid = threadIdx.x;
  const size_t MS = (size_t)MROWS * HID;
  float o[10]; float ss = 0.f;
  #pragma unroll
  for (int j = 0; j < 10; j++){
    size_t i = (size_t)r*HID + tid + j*256;
    float v = 0.f;
    #pragma unroll
    for (int s = 0; s < 8; s++) v += op[i + s*MS];
    o[j] = v; ss += v*v;
  }
  ss = bsum256(ss, buf);
  float s = rsqrtf(ss*(1.f/HID) + EPS);
  float h[10]; float s2 = 0.f;
  #pragma unroll
  for (int j = 0; j < 10; j++){
    int i = tid + j*256;
    float hv = hs[(size_t)r*HID + i] + o[j]*s*(1.f + wpost[i]);
    h[j] = hv; h2[(size_t)r*HID + i] = hv; s2 += hv*hv;
  }
  s2 = bsum256(s2, buf);
  float sc2 = rsqrtf(s2*(1.f/HID) + EPS);
  #pragma unroll
  for (int j = 0; j < 10; j++){
    int i = tid + j*256;
    xout[(size_t)r*HID + i] = f2bf(h[j]*sc2*(1.f + wpre[i]));
  }
}

// ---------------- K9: act = gelu_tanh(gate0+gate1) * (up0+up1) -> bf16 ----------------
__global__ __launch_bounds__(256) void act_fuse(
    const float* __restrict__ g, const float* __restrict__ u,
    unsigned short* __restrict__ act, int n)
{
  const size_t MS = (size_t)MROWS * INTER;
  for (int i = blockIdx.x*256 + threadIdx.x; i < n; i += gridDim.x*256){
    float x = g[i] + g[i + MS];
    float uu = u[i] + u[i + MS];
    float tt = tanhf(0.7978845608f * (x + 0.044715f * x*x*x));
    float ge = 0.5f * x * (1.f + tt);
    act[i] = f2bf(ge * uu);
  }
}

// ---------------- K11: sum down splits (8), final norm + residual ----------------
__global__ __launch_bounds__(256) void final_k(
    const float* __restrict__ dp, const float* __restrict__ h2,
    const float* __restrict__ w, float* __restrict__ out)
{
  __shared__ float buf[4];
  const int r = blockIdx.x, tid = threadIdx.x;
  const size_t MS = (size_t)MROWS * HID;
  float m[10]; float ss = 0.f;
  #pragma unroll
  for (int j = 0; j < 10; j++){
    size_t i = (size_t)r*HID + tid + j*256;
    float v = 0.f;
    #pragma unroll
    for (int s = 0; s < 8; s++) v += dp[i + s*MS];
    m[j] = v; ss += v*v;
  }
  ss = bsum256(ss, buf);
  float s = rsqrtf(ss*(1.f/HID) + EPS);
  #pragma unroll
  for (int j = 0; j < 10; j++){
    int i = tid + j*256;
    out[(size_t)r*HID + i] = h2[(size_t)r*HID + i] + m[j]*s*(1.f + w[i]);
  }
}

extern "C" void kernel_launch(void* const* d_in, const int* in_sizes, int n_in,
                              void* d_out, int out_size, void* d_ws, size_t ws_size,
                              hipStream_t stream)
{
  const float* hs     = (const float*)d_in[0];
  const float* fcos   = (const float*)d_in[1];
  const float* fsin   = (const float*)d_in[2];
  const float* w_qkv  = (const float*)d_in[8];
  const float* w_o    = (const float*)d_in[9];
  const float* qnw    = (const float*)d_in[10];
  const float* knw    = (const float*)d_in[11];
  const float* in_ln  = (const float*)d_in[12];
  const float* w_post = (const float*)d_in[13];
  const float* w_pre  = (const float*)d_in[14];
  const float* w_pffw = (const float*)d_in[15];
  const float* w_gate = (const float*)d_in[16];
  const float* w_up   = (const float*)d_in[17];
  const float* w_down = (const float*)d_in[18];
  float* out = (float*)d_out;

  char* p = (char*)d_ws;
  auto alloc = [&](size_t bytes)->void*{ void* r = p; p += (bytes + 255) & ~(size_t)255; return r; };
  const size_t SEG = (size_t)2*MROWS*INTER*4;   // 41.9MB
  unsigned short* h_b   = (unsigned short*)alloc((size_t)MROWS*HID*2);
  float* P0             = (float*)alloc(SEG);   // qkv_p then gate_p
  float* P1             = (float*)alloc(SEG);   // o_p then up_p
  float* P2             = (float*)alloc(SEG);   // down_p
  float* qbuf           = (float*)alloc((size_t)B_*NH*T_*HD*4);
  float* kT             = (float*)alloc((size_t)B_*NKV*HD*T_*4);
  float* vbuf           = (float*)alloc((size_t)B_*NKV*T_*HD*4);
  unsigned short* att_b = (unsigned short*)alloc((size_t)MROWS*2048*2);
  float* h2             = (float*)alloc((size_t)MROWS*HID*4);
  unsigned short* x_b   = (unsigned short*)alloc((size_t)MROWS*HID*2);
  unsigned short* act_b = (unsigned short*)alloc((size_t)MROWS*INTER*2);

  float* qkv_p  = P0;
  float* gate_p = P0;
  float* o_p    = P1;
  float* up_p   = P1;
  float* down_p = P2;

  rms_in<<<MROWS, 256, 0, stream>>>(hs, in_ln, h_b);
  // qkv: M=512,N=4096,K=2560 -> 256 tiles x 4 splits
  gemm_bf16<<<dim3(256, 4), 256, 0, stream>>>(h_b, w_qkv, qkv_p, 4096, 2560, 640);
  qkv_post<<<dim3(MROWS, 16), 64, 0, stream>>>(qkv_p, fcos, fsin, qnw, knw, qbuf, kT, vbuf);
  attn_fwd<<<B_*NH*T_, 128, 0, stream>>>(qbuf, kT, vbuf, att_b);
  // o: M=512,N=2560,K=2048 -> 160 tiles x 8 splits
  gemm_bf16<<<dim3(160, 8), 256, 0, stream>>>(att_b, w_o, o_p, 2560, 2048, 256);
  post_attn_k<<<MROWS, 256, 0, stream>>>(o_p, hs, w_post, w_pre, h2, x_b);
  // gate/up: M=512,N=10240,K=2560 -> 640 tiles x 2 splits
  gemm_bf16<<<dim3(640, 2), 256, 0, stream>>>(x_b, w_gate, gate_p, 10240, 2560, 1280);
  gemm_bf16<<<dim3(640, 2), 256, 0, stream>>>(x_b, w_up,   up_p,   10240, 2560, 1280);
  act_fuse<<<1024, 256, 0, stream>>>(gate_p, up_p, act_b, MROWS*INTER);
  // down: M=512,N=2560,K=10240 -> 160 tiles x 8 splits
  gemm_bf16<<<dim3(160, 8), 256, 0, stream>>>(act_b, w_down, down_p, 2560, 10240, 1280);
  final_k<<<MROWS, 256, 0, stream>>>(down_p, h2, w_pffw, out);
}

// Round 6
// 419.801 us; speedup vs baseline: 1.0894x; 1.0894x over previous
//
#include <hip/hip_runtime.h>
#include <hip/hip_bf16.h>

#define B_ 4
#define T_ 128
#define HID 2560
#define NH 8
#define NKV 4
#define HD 256
#define INTER 10240
#define MROWS 512
#define EPS 1e-6f

typedef float f32x4 __attribute__((ext_vector_type(4)));
typedef __bf16 bf16x8 __attribute__((ext_vector_type(8)));

__device__ __forceinline__ unsigned short f2bf(float f){
  unsigned int u = __builtin_bit_cast(unsigned int, f);
  u += 0x7fffu + ((u >> 16) & 1u);
  return (unsigned short)(u >> 16);
}

__device__ __forceinline__ unsigned int cvtpk(float lo, float hi){
  unsigned int r;
  asm("v_cvt_pk_bf16_f32 %0, %1, %2" : "=v"(r) : "v"(lo), "v"(hi));
  return r;
}

__device__ __forceinline__ float bsum256(float v, float* buf){
  #pragma unroll
  for (int o = 32; o; o >>= 1) v += __shfl_xor(v, o);
  __syncthreads();
  if ((threadIdx.x & 63) == 0) buf[threadIdx.x >> 6] = v;
  __syncthreads();
  return buf[0] + buf[1] + buf[2] + buf[3];
}

// ---------------- K1: input RMSNorm -> bf16 ----------------
__global__ __launch_bounds__(256) void rms_in(
    const float* __restrict__ x, const float* __restrict__ w,
    unsigned short* __restrict__ out)
{
  __shared__ float buf[4];
  const int r = blockIdx.x, tid = threadIdx.x;
  const float* xp = x + (size_t)r * HID;
  float v[10]; float ss = 0.f;
  #pragma unroll
  for (int j = 0; j < 10; j++){ v[j] = xp[tid + j*256]; ss += v[j]*v[j]; }
  ss = bsum256(ss, buf);
  float s = rsqrtf(ss * (1.f/HID) + EPS);
  #pragma unroll
  for (int j = 0; j < 10; j++){
    int i = tid + j*256;
    out[(size_t)r*HID + i] = f2bf(v[j] * s * (1.f + w[i]));
  }
}

// ---------------- GEMM: C[split][M][N] = A(bf16,[M][K]) * B(fp32,[N][K])^T ----------------
// m97-shaped: 128x128 tile, BK=32, 4 waves (2Mx2N), wave-tile 64x64 (4x4 frags,
// 16 MFMA per 8 ds_read_b128). Reg-staged with f32->bf16 convert BEFORE LDS
// store (halves B LDS bytes); padded 80B rows for bank spread; 2-phase reg
// prefetch; ONE barrier per K-step.
__global__ __launch_bounds__(256) void gemm_bf16(
    const unsigned short* __restrict__ A,
    const float* __restrict__ Bw,
    float* __restrict__ C,
    int N, int K, int klen)
{
  __shared__ unsigned short As[2][128][40];   // 10KB per buf
  __shared__ unsigned short Bs[2][128][40];   // 10KB per buf
  const int tid = threadIdx.x;
  // XCD-chunked swizzle (gridDim.x % 8 == 0), m-fastest for B-panel co-XCD
  const int bid = (blockIdx.x & 7) * ((int)gridDim.x >> 3) + (blockIdx.x >> 3);
  const int bm = (bid & 3) << 7;
  const int bn = (bid >> 2) << 7;
  const int k0 = blockIdx.y * klen;
  const int nt = klen >> 5;

  const int srow = tid >> 1;            // 0..127
  const int shalf = tid & 1;            // 16-short halves of the 32-short row
  const unsigned short* ApG = A + (size_t)(bm + srow) * K + k0 + (shalf << 4);
  const float*          BpG = Bw + (size_t)(bn + srow) * K + k0 + (shalf << 4);

  const int wave = tid >> 6, lane = tid & 63;
  const int wm = (wave & 1) << 6;
  const int wn = (wave >> 1) << 6;
  const int fr = lane & 15, kq = lane >> 4;

  f32x4 acc[4][4];
  #pragma unroll
  for (int i = 0; i < 4; i++)
    #pragma unroll
    for (int j = 0; j < 4; j++)
      #pragma unroll
      for (int e = 0; e < 4; e++) acc[i][j][e] = 0.f;

  // prologue: issue loads for tile 0
  uint4  ra0 = *(const uint4*)(ApG);
  uint4  ra1 = *(const uint4*)(ApG + 8);
  float4 rb0 = *(const float4*)(BpG);
  float4 rb1 = *(const float4*)(BpG + 4);
  float4 rb2 = *(const float4*)(BpG + 8);
  float4 rb3 = *(const float4*)(BpG + 12);

  int cur = 0;
  for (int t = 0; t < nt; t++) {
    // ---- stage tile t: convert B to bf16, write both to LDS[cur] ----
    uint4 w0, w1;
    w0.x = cvtpk(rb0.x, rb0.y); w0.y = cvtpk(rb0.z, rb0.w);
    w0.z = cvtpk(rb1.x, rb1.y); w0.w = cvtpk(rb1.z, rb1.w);
    w1.x = cvtpk(rb2.x, rb2.y); w1.y = cvtpk(rb2.z, rb2.w);
    w1.z = cvtpk(rb3.x, rb3.y); w1.w = cvtpk(rb3.z, rb3.w);
    *(uint4*)&As[cur][srow][(shalf<<4)]     = ra0;
    *(uint4*)&As[cur][srow][(shalf<<4) + 8] = ra1;
    *(uint4*)&Bs[cur][srow][(shalf<<4)]     = w0;
    *(uint4*)&Bs[cur][srow][(shalf<<4) + 8] = w1;
    __syncthreads();
    // ---- issue loads for tile t+1 (overlap with COMPUTE below) ----
    if (t + 1 < nt) {
      const unsigned short* a2 = ApG + ((t + 1) << 5);
      const float*          b2 = BpG + ((t + 1) << 5);
      ra0 = *(const uint4*)(a2);
      ra1 = *(const uint4*)(a2 + 8);
      rb0 = *(const float4*)(b2);
      rb1 = *(const float4*)(b2 + 4);
      rb2 = *(const float4*)(b2 + 8);
      rb3 = *(const float4*)(b2 + 12);
    }
    // ---- compute tile t: 8 ds_read_b128 -> 16 MFMA ----
    bf16x8 af[4], bfv[4];
    #pragma unroll
    for (int mi = 0; mi < 4; mi++) af[mi]  = *(const bf16x8*)&As[cur][wm + mi*16 + fr][kq*8];
    #pragma unroll
    for (int ni = 0; ni < 4; ni++) bfv[ni] = *(const bf16x8*)&Bs[cur][wn + ni*16 + fr][kq*8];
    #pragma unroll
    for (int mi = 0; mi < 4; mi++)
      #pragma unroll
      for (int ni = 0; ni < 4; ni++)
        acc[mi][ni] = __builtin_amdgcn_mfma_f32_16x16x32_bf16(af[mi], bfv[ni], acc[mi][ni], 0, 0, 0);
    cur ^= 1;
  }

  float* Cp = C + (size_t)blockIdx.y * MROWS * N;
  #pragma unroll
  for (int mi = 0; mi < 4; mi++) {
    #pragma unroll
    for (int ni = 0; ni < 4; ni++) {
      int m = bm + wm + mi*16 + kq*4;
      int n = bn + wn + ni*16 + fr;
      #pragma unroll
      for (int i = 0; i < 4; i++)
        Cp[(size_t)(m + i) * N + n] = acc[mi][ni][i];
    }
  }
}

// ---------------- K3: sum qkv splits (4), QK-norm, RoPE, scatter to q / kT / v ----------------
__global__ __launch_bounds__(64) void qkv_post(
    const float* __restrict__ qkvp,   // [4][512][4096]
    const float* __restrict__ fcos, const float* __restrict__ fsin,
    const float* __restrict__ qnw, const float* __restrict__ knw,
    float* __restrict__ qout, float* __restrict__ kT, float* __restrict__ vout)
{
  const int row = blockIdx.x;
  const int hh  = blockIdx.y;
  const int b = row >> 7, t = row & 127;
  const int l = threadIdx.x;
  const size_t MS = (size_t)MROWS * 4096;
  const float* src = qkvp + (size_t)row * 4096 + hh * 256;
  float x[4];
  #pragma unroll
  for (int j = 0; j < 4; j++){
    int d = l + j*64;
    x[j] = src[d] + src[d + MS] + src[d + 2*MS] + src[d + 3*MS];
  }
  if (hh >= 12) {
    float* vp = vout + ((size_t)(b*NKV + (hh-12)) * T_ + t) * HD;
    #pragma unroll
    for (int j = 0; j < 4; j++) vp[l + j*64] = x[j];
    return;
  }
  float ss = x[0]*x[0] + x[1]*x[1] + x[2]*x[2] + x[3]*x[3];
  #pragma unroll
  for (int o = 32; o; o >>= 1) ss += __shfl_xor(ss, o);
  float r = rsqrtf(ss * (1.f/HD) + EPS);
  const float* nw = (hh < 8) ? qnw : knw;
  #pragma unroll
  for (int j = 0; j < 4; j++){ int d = l + j*64; x[j] = x[j] * r * (1.f + nw[d]); }
  float c0 = fcos[t*128 + l],      s0 = fsin[t*128 + l];
  float c1 = fcos[t*128 + l + 64], s1 = fsin[t*128 + l + 64];
  float y0 = x[0]*c0 - x[2]*s0;
  float y2 = x[0]*s0 + x[2]*c0;
  float y1 = x[1]*c1 - x[3]*s1;
  float y3 = x[1]*s1 + x[3]*c1;
  if (hh < 8) {
    float* qp = qout + ((size_t)(b*NH + hh) * T_ + t) * HD;
    const float sc = 0.0625f;
    qp[l] = y0*sc; qp[l+64] = y1*sc; qp[l+128] = y2*sc; qp[l+192] = y3*sc;
  } else {
    float* kp = kT + (size_t)(b*NKV + (hh-8)) * HD * T_;
    kp[(size_t)(l)*T_ + t] = y0;  kp[(size_t)(l+64)*T_ + t] = y1;
    kp[(size_t)(l+128)*T_ + t] = y2; kp[(size_t)(l+192)*T_ + t] = y3;
  }
}

// ---------------- K4: causal attention over the 128 written positions ----------------
__global__ __launch_bounds__(128) void attn_fwd(
    const float* __restrict__ q, const float* __restrict__ kT,
    const float* __restrict__ V, unsigned short* __restrict__ attn_out)
{
  const int id = blockIdx.x;
  const int t = id & 127;
  const int h = (id >> 7) & 7;
  const int b = id >> 10;
  const int kvh = h >> 1;
  const int tid = threadIdx.x;
  __shared__ float qs[256];
  __shared__ float sc[128];
  __shared__ float red[128];
  const float* qp = q + (size_t)id * HD;
  qs[tid] = qp[tid]; qs[tid + 128] = qp[tid + 128];
  __syncthreads();
  const float* kp = kT + (size_t)(b*NKV + kvh) * HD * T_;
  float dot = 0.f;
  const bool valid = (tid <= t);
  if (valid) {
    #pragma unroll 8
    for (int d = 0; d < 256; d++) dot += qs[d] * kp[(size_t)d*T_ + tid];
  }
  float score = valid ? 50.f * tanhf(dot * 0.02f) : -3.0e38f;
  sc[tid] = score; red[tid] = score;
  __syncthreads();
  for (int o = 64; o; o >>= 1){ if (tid < o) red[tid] = fmaxf(red[tid], red[tid+o]); __syncthreads(); }
  float m = red[0];
  __syncthreads();
  float p = valid ? __expf(score - m) : 0.f;
  sc[tid] = p; red[tid] = p;
  __syncthreads();
  for (int o = 64; o; o >>= 1){ if (tid < o) red[tid] += red[tid+o]; __syncthreads(); }
  float inv = 1.f / red[0];
  const float* vp = V + (size_t)(b*NKV + kvh) * T_ * HD;
  float a0 = 0.f, a1 = 0.f;
  for (int s = 0; s <= t; s++){
    float ps = sc[s];
    a0 += ps * vp[(size_t)s*HD + tid];
    a1 += ps * vp[(size_t)s*HD + tid + 128];
  }
  size_t orow = ((size_t)(b*T_ + t)) * 2048 + h * 256;
  attn_out[orow + tid]       = f2bf(a0 * inv);
  attn_out[orow + tid + 128] = f2bf(a1 * inv);
}

// ---------------- K6: sum o splits (4), post-attn norm + residual, pre-ffw norm -> bf16 ----------------
__global__ __launch_bounds__(256) void post_attn_k(
    const float* __restrict__ op, const float* __restrict__ hs,
    const float* __restrict__ wpost, const float* __restrict__ wpre,
    float* __restrict__ h2, unsigned short* __restrict__ xout)
{
  __shared__ float buf[4];
  const int r = blockIdx.x, tid = threadIdx.x;
  const size_t MS = (size_t)MROWS * HID;
  float o[10]; float ss = 0.f;
  #pragma unroll
  for (int j = 0; j < 10; j++){
    size_t i = (size_t)r*HID + tid + j*256;
    float v = op[i] + op[i+MS] + op[i+2*MS] + op[i+3*MS];
    o[j] = v; ss += v*v;
  }
  ss = bsum256(ss, buf);
  float s = rsqrtf(ss*(1.f/HID) + EPS);
  float h[10]; float s2 = 0.f;
  #pragma unroll
  for (int j = 0; j < 10; j++){
    int i = tid + j*256;
    float hv = hs[(size_t)r*HID + i] + o[j]*s*(1.f + wpost[i]);
    h[j] = hv; h2[(size_t)r*HID + i] = hv; s2 += hv*hv;
  }
  s2 = bsum256(s2, buf);
  float sc2 = rsqrtf(s2*(1.f/HID) + EPS);
  #pragma unroll
  for (int j = 0; j < 10; j++){
    int i = tid + j*256;
    xout[(size_t)r*HID + i] = f2bf(h[j]*sc2*(1.f + wpre[i]));
  }
}

// ---------------- K9: act = gelu_tanh(gate0+gate1) * (up0+up1) -> bf16 ----------------
__global__ __launch_bounds__(256) void act_fuse(
    const float* __restrict__ g, const float* __restrict__ u,
    unsigned short* __restrict__ act, int n)
{
  const size_t MS = (size_t)MROWS * INTER;
  for (int i = blockIdx.x*256 + threadIdx.x; i < n; i += gridDim.x*256){
    float x = g[i] + g[i + MS];
    float uu = u[i] + u[i + MS];
    float tt = tanhf(0.7978845608f * (x + 0.044715f * x*x*x));
    float ge = 0.5f * x * (1.f + tt);
    act[i] = f2bf(ge * uu);
  }
}

// ---------------- K11: sum down splits (8), final norm + residual ----------------
__global__ __launch_bounds__(256) void final_k(
    const float* __restrict__ dp, const float* __restrict__ h2,
    const float* __restrict__ w, float* __restrict__ out)
{
  __shared__ float buf[4];
  const int r = blockIdx.x, tid = threadIdx.x;
  const size_t MS = (size_t)MROWS * HID;
  float m[10]; float ss = 0.f;
  #pragma unroll
  for (int j = 0; j < 10; j++){
    size_t i = (size_t)r*HID + tid + j*256;
    float v = 0.f;
    #pragma unroll
    for (int s = 0; s < 8; s++) v += dp[i + s*MS];
    m[j] = v; ss += v*v;
  }
  ss = bsum256(ss, buf);
  float s = rsqrtf(ss*(1.f/HID) + EPS);
  #pragma unroll
  for (int j = 0; j < 10; j++){
    int i = tid + j*256;
    out[(size_t)r*HID + i] = h2[(size_t)r*HID + i] + m[j]*s*(1.f + w[i]);
  }
}

extern "C" void kernel_launch(void* const* d_in, const int* in_sizes, int n_in,
                              void* d_out, int out_size, void* d_ws, size_t ws_size,
                              hipStream_t stream)
{
  const float* hs     = (const float*)d_in[0];
  const float* fcos   = (const float*)d_in[1];
  const float* fsin   = (const float*)d_in[2];
  const float* w_qkv  = (const float*)d_in[8];
  const float* w_o    = (const float*)d_in[9];
  const float* qnw    = (const float*)d_in[10];
  const float* knw    = (const float*)d_in[11];
  const float* in_ln  = (const float*)d_in[12];
  const float* w_post = (const float*)d_in[13];
  const float* w_pre  = (const float*)d_in[14];
  const float* w_pffw = (const float*)d_in[15];
  const float* w_gate = (const float*)d_in[16];
  const float* w_up   = (const float*)d_in[17];
  const float* w_down = (const float*)d_in[18];
  float* out = (float*)d_out;

  char* p = (char*)d_ws;
  auto alloc = [&](size_t bytes)->void*{ void* r = p; p += (bytes + 255) & ~(size_t)255; return r; };
  const size_t SEG = (size_t)2*MROWS*INTER*4;   // 41.9MB
  unsigned short* h_b   = (unsigned short*)alloc((size_t)MROWS*HID*2);
  float* P0             = (float*)alloc(SEG);   // qkv_p then gate_p
  float* P1             = (float*)alloc(SEG);   // o_p then up_p
  float* P2             = (float*)alloc(SEG);   // down_p
  float* qbuf           = (float*)alloc((size_t)B_*NH*T_*HD*4);
  float* kT             = (float*)alloc((size_t)B_*NKV*HD*T_*4);
  float* vbuf           = (float*)alloc((size_t)B_*NKV*T_*HD*4);
  unsigned short* att_b = (unsigned short*)alloc((size_t)MROWS*2048*2);
  float* h2             = (float*)alloc((size_t)MROWS*HID*4);
  unsigned short* x_b   = (unsigned short*)alloc((size_t)MROWS*HID*2);
  unsigned short* act_b = (unsigned short*)alloc((size_t)MROWS*INTER*2);

  float* qkv_p  = P0;
  float* gate_p = P0;
  float* o_p    = P1;
  float* up_p   = P1;
  float* down_p = P2;

  rms_in<<<MROWS, 256, 0, stream>>>(hs, in_ln, h_b);
  // qkv: M=512,N=4096,K=2560 -> (4m x 32n)=128 tiles x 4 splits = 512 blocks
  gemm_bf16<<<dim3(128, 4), 256, 0, stream>>>(h_b, w_qkv, qkv_p, 4096, 2560, 640);
  qkv_post<<<dim3(MROWS, 16), 64, 0, stream>>>(qkv_p, fcos, fsin, qnw, knw, qbuf, kT, vbuf);
  attn_fwd<<<B_*NH*T_, 128, 0, stream>>>(qbuf, kT, vbuf, att_b);
  // o: M=512,N=2560,K=2048 -> (4 x 20)=80 tiles x 4 splits = 320 blocks
  gemm_bf16<<<dim3(80, 4), 256, 0, stream>>>(att_b, w_o, o_p, 2560, 2048, 512);
  post_attn_k<<<MROWS, 256, 0, stream>>>(o_p, hs, w_post, w_pre, h2, x_b);
  // gate/up: M=512,N=10240,K=2560 -> (4 x 80)=320 tiles x 2 splits = 640 blocks
  gemm_bf16<<<dim3(320, 2), 256, 0, stream>>>(x_b, w_gate, gate_p, 10240, 2560, 1280);
  gemm_bf16<<<dim3(320, 2), 256, 0, stream>>>(x_b, w_up,   up_p,   10240, 2560, 1280);
  act_fuse<<<1024, 256, 0, stream>>>(gate_p, up_p, act_b, MROWS*INTER);
  // down: M=512,N=2560,K=10240 -> 80 tiles x 8 splits = 640 blocks
  gemm_bf16<<<dim3(80, 8), 256, 0, stream>>>(act_b, w_down, down_p, 2560, 10240, 1280);
  final_k<<<MROWS, 256, 0, stream>>>(down_p, h2, w_pffw, out);
}

// Round 7
// 399.531 us; speedup vs baseline: 1.1447x; 1.0507x over previous
//
#include <hip/hip_runtime.h>
#include <hip/hip_bf16.h>

#define B_ 4
#define T_ 128
#define HID 2560
#define NH 8
#define NKV 4
#define HD 256
#define INTER 10240
#define MROWS 512
#define EPS 1e-6f

typedef float f32x4 __attribute__((ext_vector_type(4)));
typedef __bf16 bf16x8 __attribute__((ext_vector_type(8)));

__device__ __forceinline__ unsigned short f2bf(float f){
  unsigned int u = __builtin_bit_cast(unsigned int, f);
  u += 0x7fffu + ((u >> 16) & 1u);
  return (unsigned short)(u >> 16);
}
__device__ __forceinline__ float bf2f(unsigned short u){
  unsigned int x = ((unsigned int)u) << 16;
  return __builtin_bit_cast(float, x);
}
__device__ __forceinline__ unsigned int cvtpk(float lo, float hi){
  unsigned int r;
  asm("v_cvt_pk_bf16_f32 %0, %1, %2" : "=v"(r) : "v"(lo), "v"(hi));
  return r;
}

__device__ __forceinline__ float bsum256(float v, float* buf){
  #pragma unroll
  for (int o = 32; o; o >>= 1) v += __shfl_xor(v, o);
  __syncthreads();
  if ((threadIdx.x & 63) == 0) buf[threadIdx.x >> 6] = v;
  __syncthreads();
  return buf[0] + buf[1] + buf[2] + buf[3];
}

// ---------------- K1: input RMSNorm -> bf16 ----------------
__global__ __launch_bounds__(256) void rms_in(
    const float* __restrict__ x, const float* __restrict__ w,
    unsigned short* __restrict__ out)
{
  __shared__ float buf[4];
  const int r = blockIdx.x, tid = threadIdx.x;
  const float* xp = x + (size_t)r * HID;
  float v[10]; float ss = 0.f;
  #pragma unroll
  for (int j = 0; j < 10; j++){ v[j] = xp[tid + j*256]; ss += v[j]*v[j]; }
  ss = bsum256(ss, buf);
  float s = rsqrtf(ss * (1.f/HID) + EPS);
  #pragma unroll
  for (int j = 0; j < 10; j++){
    int i = tid + j*256;
    out[(size_t)r*HID + i] = f2bf(v[j] * s * (1.f + w[i]));
  }
}

// ---------------- GEMM: C[split][M][N] = A(bf16,[M][K]) * B(fp32,[N][K])^T ----------
// 256Mx128N block-tile, wave-tile 128x64 (4 waves 2Mx2N), BK=32.
// 32 MFMA per 12 ds_read_b128 per wave-step (1.8x FLOP/LDS-byte vs 64x64).
// Reg-staged, f32->bf16 convert before LDS store, 80B padded rows, dbuf,
// ONE barrier per K-step. Optional second weight matrix for n >= n_hi
// (fused gate+up). BF16OUT selects bf16 partial output.
template<bool BF16OUT>
__global__ __launch_bounds__(256, 2) void gemm_big(
    const unsigned short* __restrict__ A,
    const float* __restrict__ B0,
    const float* __restrict__ B1,
    int n_hi,
    void* __restrict__ Cv,
    int N, int K, int klen)
{
  __shared__ unsigned short As[2][256][40];   // 20KB per buf
  __shared__ unsigned short Bs[2][128][40];   // 10KB per buf
  const int tid = threadIdx.x;
  // XCD-chunked swizzle (gridDim.x % 8 == 0); m-fastest -> B-panel co-XCD
  const int bid = (blockIdx.x & 7) * ((int)gridDim.x >> 3) + (blockIdx.x >> 3);
  const int bm = (bid & 1) << 8;
  const int bn = (bid >> 1) << 7;
  const int k0 = blockIdx.y * klen;
  const int nt = klen >> 5;

  const int srow = tid >> 1, shalf = tid & 1;
  const size_t A128 = (size_t)128 * K;
  const unsigned short* ApG = A + (size_t)(bm + srow) * K + k0 + (shalf << 4);
  const float* Bb = (bn < n_hi) ? B0 : B1;
  const int bnr = (bn < n_hi) ? bn : (bn - n_hi);
  const float* BpG = Bb + (size_t)(bnr + srow) * K + k0 + (shalf << 4);

  const int wave = tid >> 6, lane = tid & 63;
  const int wm = (wave & 1) << 7;   // 0 / 128
  const int wn = (wave >> 1) << 6;  // 0 / 64
  const int fr = lane & 15, kq = lane >> 4;

  f32x4 acc[8][4];
  #pragma unroll
  for (int i = 0; i < 8; i++)
    #pragma unroll
    for (int j = 0; j < 4; j++)
      #pragma unroll
      for (int e = 0; e < 4; e++) acc[i][j][e] = 0.f;

  // prologue: loads for tile 0
  uint4  ra0 = *(const uint4*)(ApG);
  uint4  ra1 = *(const uint4*)(ApG + 8);
  uint4  ra2 = *(const uint4*)(ApG + A128);
  uint4  ra3 = *(const uint4*)(ApG + A128 + 8);
  float4 rb0 = *(const float4*)(BpG);
  float4 rb1 = *(const float4*)(BpG + 4);
  float4 rb2 = *(const float4*)(BpG + 8);
  float4 rb3 = *(const float4*)(BpG + 12);

  int cur = 0;
  for (int t = 0; t < nt; t++) {
    uint4 w0, w1;
    w0.x = cvtpk(rb0.x, rb0.y); w0.y = cvtpk(rb0.z, rb0.w);
    w0.z = cvtpk(rb1.x, rb1.y); w0.w = cvtpk(rb1.z, rb1.w);
    w1.x = cvtpk(rb2.x, rb2.y); w1.y = cvtpk(rb2.z, rb2.w);
    w1.z = cvtpk(rb3.x, rb3.y); w1.w = cvtpk(rb3.z, rb3.w);
    *(uint4*)&As[cur][srow      ][(shalf<<4)]     = ra0;
    *(uint4*)&As[cur][srow      ][(shalf<<4) + 8] = ra1;
    *(uint4*)&As[cur][srow + 128][(shalf<<4)]     = ra2;
    *(uint4*)&As[cur][srow + 128][(shalf<<4) + 8] = ra3;
    *(uint4*)&Bs[cur][srow][(shalf<<4)]     = w0;
    *(uint4*)&Bs[cur][srow][(shalf<<4) + 8] = w1;
    __syncthreads();
    if (t + 1 < nt) {
      const unsigned short* a2 = ApG + ((t + 1) << 5);
      const float*          b2 = BpG + ((t + 1) << 5);
      ra0 = *(const uint4*)(a2);
      ra1 = *(const uint4*)(a2 + 8);
      ra2 = *(const uint4*)(a2 + A128);
      ra3 = *(const uint4*)(a2 + A128 + 8);
      rb0 = *(const float4*)(b2);
      rb1 = *(const float4*)(b2 + 4);
      rb2 = *(const float4*)(b2 + 8);
      rb3 = *(const float4*)(b2 + 12);
    }
    bf16x8 af[8], bfv[4];
    #pragma unroll
    for (int mi = 0; mi < 8; mi++) af[mi]  = *(const bf16x8*)&As[cur][wm + mi*16 + fr][kq*8];
    #pragma unroll
    for (int ni = 0; ni < 4; ni++) bfv[ni] = *(const bf16x8*)&Bs[cur][wn + ni*16 + fr][kq*8];
    #pragma unroll
    for (int mi = 0; mi < 8; mi++)
      #pragma unroll
      for (int ni = 0; ni < 4; ni++)
        acc[mi][ni] = __builtin_amdgcn_mfma_f32_16x16x32_bf16(af[mi], bfv[ni], acc[mi][ni], 0, 0, 0);
    cur ^= 1;
  }

  #pragma unroll
  for (int mi = 0; mi < 8; mi++) {
    #pragma unroll
    for (int ni = 0; ni < 4; ni++) {
      int m = bm + wm + mi*16 + kq*4;
      int n = bn + wn + ni*16 + fr;
      if (BF16OUT) {
        unsigned short* Cp = (unsigned short*)Cv + (size_t)blockIdx.y * MROWS * N;
        #pragma unroll
        for (int i = 0; i < 4; i++)
          Cp[(size_t)(m + i) * N + n] = f2bf(acc[mi][ni][i]);
      } else {
        float* Cp = (float*)Cv + (size_t)blockIdx.y * MROWS * N;
        #pragma unroll
        for (int i = 0; i < 4; i++)
          Cp[(size_t)(m + i) * N + n] = acc[mi][ni][i];
      }
    }
  }
}

// ---------------- K3: sum qkv splits (4), QK-norm, RoPE, scatter to q / kT / v ----------------
__global__ __launch_bounds__(64) void qkv_post(
    const float* __restrict__ qkvp,   // [4][512][4096]
    const float* __restrict__ fcos, const float* __restrict__ fsin,
    const float* __restrict__ qnw, const float* __restrict__ knw,
    float* __restrict__ qout, float* __restrict__ kT, float* __restrict__ vout)
{
  const int row = blockIdx.x;
  const int hh  = blockIdx.y;
  const int b = row >> 7, t = row & 127;
  const int l = threadIdx.x;
  const size_t MS = (size_t)MROWS * 4096;
  const float* src = qkvp + (size_t)row * 4096 + hh * 256;
  float x[4];
  #pragma unroll
  for (int j = 0; j < 4; j++){
    int d = l + j*64;
    x[j] = src[d] + src[d + MS] + src[d + 2*MS] + src[d + 3*MS];
  }
  if (hh >= 12) {
    float* vp = vout + ((size_t)(b*NKV + (hh-12)) * T_ + t) * HD;
    #pragma unroll
    for (int j = 0; j < 4; j++) vp[l + j*64] = x[j];
    return;
  }
  float ss = x[0]*x[0] + x[1]*x[1] + x[2]*x[2] + x[3]*x[3];
  #pragma unroll
  for (int o = 32; o; o >>= 1) ss += __shfl_xor(ss, o);
  float r = rsqrtf(ss * (1.f/HD) + EPS);
  const float* nw = (hh < 8) ? qnw : knw;
  #pragma unroll
  for (int j = 0; j < 4; j++){ int d = l + j*64; x[j] = x[j] * r * (1.f + nw[d]); }
  float c0 = fcos[t*128 + l],      s0 = fsin[t*128 + l];
  float c1 = fcos[t*128 + l + 64], s1 = fsin[t*128 + l + 64];
  float y0 = x[0]*c0 - x[2]*s0;
  float y2 = x[0]*s0 + x[2]*c0;
  float y1 = x[1]*c1 - x[3]*s1;
  float y3 = x[1]*s1 + x[3]*c1;
  if (hh < 8) {
    float* qp = qout + ((size_t)(b*NH + hh) * T_ + t) * HD;
    const float sc = 0.0625f;
    qp[l] = y0*sc; qp[l+64] = y1*sc; qp[l+128] = y2*sc; qp[l+192] = y3*sc;
  } else {
    float* kp = kT + (size_t)(b*NKV + (hh-8)) * HD * T_;
    kp[(size_t)(l)*T_ + t] = y0;  kp[(size_t)(l+64)*T_ + t] = y1;
    kp[(size_t)(l+128)*T_ + t] = y2; kp[(size_t)(l+192)*T_ + t] = y3;
  }
}

// ---------------- K4: causal attention over the 128 written positions ----------------
__global__ __launch_bounds__(128) void attn_fwd(
    const float* __restrict__ q, const float* __restrict__ kT,
    const float* __restrict__ V, unsigned short* __restrict__ attn_out)
{
  const int id = blockIdx.x;
  const int t = id & 127;
  const int h = (id >> 7) & 7;
  const int b = id >> 10;
  const int kvh = h >> 1;
  const int tid = threadIdx.x;
  __shared__ float qs[256];
  __shared__ float sc[128];
  __shared__ float red[128];
  const float* qp = q + (size_t)id * HD;
  qs[tid] = qp[tid]; qs[tid + 128] = qp[tid + 128];
  __syncthreads();
  const float* kp = kT + (size_t)(b*NKV + kvh) * HD * T_;
  float dot = 0.f;
  const bool valid = (tid <= t);
  if (valid) {
    #pragma unroll 8
    for (int d = 0; d < 256; d++) dot += qs[d] * kp[(size_t)d*T_ + tid];
  }
  float score = valid ? 50.f * tanhf(dot * 0.02f) : -3.0e38f;
  sc[tid] = score; red[tid] = score;
  __syncthreads();
  for (int o = 64; o; o >>= 1){ if (tid < o) red[tid] = fmaxf(red[tid], red[tid+o]); __syncthreads(); }
  float m = red[0];
  __syncthreads();
  float p = valid ? __expf(score - m) : 0.f;
  sc[tid] = p; red[tid] = p;
  __syncthreads();
  for (int o = 64; o; o >>= 1){ if (tid < o) red[tid] += red[tid+o]; __syncthreads(); }
  float inv = 1.f / red[0];
  const float* vp = V + (size_t)(b*NKV + kvh) * T_ * HD;
  float a0 = 0.f, a1 = 0.f;
  for (int s = 0; s <= t; s++){
    float ps = sc[s];
    a0 += ps * vp[(size_t)s*HD + tid];
    a1 += ps * vp[(size_t)s*HD + tid + 128];
  }
  size_t orow = ((size_t)(b*T_ + t)) * 2048 + h * 256;
  attn_out[orow + tid]       = f2bf(a0 * inv);
  attn_out[orow + tid + 128] = f2bf(a1 * inv);
}

// ---------------- K6: sum o splits (8), post-attn norm + residual, pre-ffw norm -> bf16 ----------------
__global__ __launch_bounds__(256) void post_attn_k(
    const float* __restrict__ op, const float* __restrict__ hs,
    const float* __restrict__ wpost, const float* __restrict__ wpre,
    float* __restrict__ h2, unsigned short* __restrict__ xout)
{
  __shared__ float buf[4];
  const int r = blockIdx.x, tid = threadIdx.x;
  const size_t MS = (size_t)MROWS * HID;
  float o[10]; float ss = 0.f;
  #pragma unroll
  for (int j = 0; j < 10; j++){
    size_t i = (size_t)r*HID + tid + j*256;
    float v = 0.f;
    #pragma unroll
    for (int s = 0; s < 8; s++) v += op[i + s*MS];
    o[j] = v; ss += v*v;
  }
  ss = bsum256(ss, buf);
  float s = rsqrtf(ss*(1.f/HID) + EPS);
  float h[10]; float s2 = 0.f;
  #pragma unroll
  for (int j = 0; j < 10; j++){
    int i = tid + j*256;
    float hv = hs[(size_t)r*HID + i] + o[j]*s*(1.f + wpost[i]);
    h[j] = hv; h2[(size_t)r*HID + i] = hv; s2 += hv*hv;
  }
  s2 = bsum256(s2, buf);
  float sc2 = rsqrtf(s2*(1.f/HID) + EPS);
  #pragma unroll
  for (int j = 0; j < 10; j++){
    int i = tid + j*256;
    xout[(size_t)r*HID + i] = f2bf(h[j]*sc2*(1.f + wpre[i]));
  }
}

// ---------------- K9: act = gelu_tanh(sum gate) * (sum up) from fused bf16 partials ----------------
__global__ __launch_bounds__(256) void act_fuse(
    const unsigned short* __restrict__ gu,   // [4][512][20480] bf16
    unsigned short* __restrict__ act)        // [512][10240] bf16
{
  const int r = blockIdx.x;
  const size_t MS = (size_t)MROWS * 20480;
  const unsigned short* rowp = gu + (size_t)r * 20480;
  for (int c = threadIdx.x; c < INTER; c += 256){
    float g = 0.f, u = 0.f;
    #pragma unroll
    for (int s = 0; s < 4; s++){
      g += bf2f(rowp[s*MS + c]);
      u += bf2f(rowp[s*MS + c + INTER]);
    }
    float tt = tanhf(0.7978845608f * (g + 0.044715f * g*g*g));
    float ge = 0.5f * g * (1.f + tt);
    act[(size_t)r*INTER + c] = f2bf(ge * u);
  }
}

// ---------------- K11: sum down splits (8), final norm + residual ----------------
__global__ __launch_bounds__(256) void final_k(
    const float* __restrict__ dp, const float* __restrict__ h2,
    const float* __restrict__ w, float* __restrict__ out)
{
  __shared__ float buf[4];
  const int r = blockIdx.x, tid = threadIdx.x;
  const size_t MS = (size_t)MROWS * HID;
  float m[10]; float ss = 0.f;
  #pragma unroll
  for (int j = 0; j < 10; j++){
    size_t i = (size_t)r*HID + tid + j*256;
    float v = 0.f;
    #pragma unroll
    for (int s = 0; s < 8; s++) v += dp[i + s*MS];
    m[j] = v; ss += v*v;
  }
  ss = bsum256(ss, buf);
  float s = rsqrtf(ss*(1.f/HID) + EPS);
  #pragma unroll
  for (int j = 0; j < 10; j++){
    int i = tid + j*256;
    out[(size_t)r*HID + i] = h2[(size_t)r*HID + i] + m[j]*s*(1.f + w[i]);
  }
}

extern "C" void kernel_launch(void* const* d_in, const int* in_sizes, int n_in,
                              void* d_out, int out_size, void* d_ws, size_t ws_size,
                              hipStream_t stream)
{
  const float* hs     = (const float*)d_in[0];
  const float* fcos   = (const float*)d_in[1];
  const float* fsin   = (const float*)d_in[2];
  const float* w_qkv  = (const float*)d_in[8];
  const float* w_o    = (const float*)d_in[9];
  const float* qnw    = (const float*)d_in[10];
  const float* knw    = (const float*)d_in[11];
  const float* in_ln  = (const float*)d_in[12];
  const float* w_post = (const float*)d_in[13];
  const float* w_pre  = (const float*)d_in[14];
  const float* w_pffw = (const float*)d_in[15];
  const float* w_gate = (const float*)d_in[16];
  const float* w_up   = (const float*)d_in[17];
  const float* w_down = (const float*)d_in[18];
  float* out = (float*)d_out;

  char* p = (char*)d_ws;
  auto alloc = [&](size_t bytes)->void*{ void* r = p; p += (bytes + 255) & ~(size_t)255; return r; };
  // P0: qkv_p fp32 [4][512][4096] (33.5MB)  then  gu_p bf16 [4][512][20480] (84MB)
  void* P0 = alloc((size_t)4*MROWS*20480*2);
  // P1: o_p fp32 [8][512][2560] (42MB)      then  down_p fp32 [8][512][2560] (42MB)
  void* P1 = alloc((size_t)8*MROWS*HID*4);
  unsigned short* h_b   = (unsigned short*)alloc((size_t)MROWS*HID*2);
  float* qbuf           = (float*)alloc((size_t)B_*NH*T_*HD*4);
  float* kT             = (float*)alloc((size_t)B_*NKV*HD*T_*4);
  float* vbuf           = (float*)alloc((size_t)B_*NKV*T_*HD*4);
  unsigned short* att_b = (unsigned short*)alloc((size_t)MROWS*2048*2);
  float* h2             = (float*)alloc((size_t)MROWS*HID*4);
  unsigned short* x_b   = (unsigned short*)alloc((size_t)MROWS*HID*2);
  unsigned short* act_b = (unsigned short*)alloc((size_t)MROWS*INTER*2);

  float* qkv_p          = (float*)P0;
  unsigned short* gu_p  = (unsigned short*)P0;
  float* o_p            = (float*)P1;
  float* down_p         = (float*)P1;

  rms_in<<<MROWS, 256, 0, stream>>>(hs, in_ln, h_b);
  // qkv: M=512,N=4096,K=2560 -> (2m x 32n)=64 tiles x 4 splits
  gemm_big<false><<<dim3(64, 4), 256, 0, stream>>>(h_b, w_qkv, w_qkv, 1<<30, qkv_p, 4096, 2560, 640);
  qkv_post<<<dim3(MROWS, 16), 64, 0, stream>>>(qkv_p, fcos, fsin, qnw, knw, qbuf, kT, vbuf);
  attn_fwd<<<B_*NH*T_, 128, 0, stream>>>(qbuf, kT, vbuf, att_b);
  // o: M=512,N=2560,K=2048 -> (2 x 20)=40 tiles x 8 splits
  gemm_big<false><<<dim3(40, 8), 256, 0, stream>>>(att_b, w_o, w_o, 1<<30, o_p, 2560, 2048, 256);
  post_attn_k<<<MROWS, 256, 0, stream>>>(o_p, hs, w_post, w_pre, h2, x_b);
  // fused gate+up: M=512,N=20480,K=2560 -> (2 x 160)=320 tiles x 4 splits, bf16 partials
  gemm_big<true><<<dim3(320, 4), 256, 0, stream>>>(x_b, w_gate, w_up, 10240, gu_p, 20480, 2560, 640);
  act_fuse<<<MROWS, 256, 0, stream>>>(gu_p, act_b);
  // down: M=512,N=2560,K=10240 -> 40 tiles x 8 splits
  gemm_big<false><<<dim3(40, 8), 256, 0, stream>>>(act_b, w_down, w_down, 1<<30, down_p, 2560, 10240, 1280);
  final_k<<<MROWS, 256, 0, stream>>>(down_p, h2, w_pffw, out);
}